// Round 1
// 420.094 us; speedup vs baseline: 1.0681x; 1.0681x over previous
//
#include <hip/hip_runtime.h>
#include <math.h>

#define N_TOKENS 16384
#define D_MODEL  4096
#define N_EXP    64

#define BK   16                 // k-depth per LDS tile
#define LD   68                 // LDS leading dim: 64 + 4 pad (keeps 16B align, 2-way banks)
#define KW   (D_MODEL / 4)      // 1024 k per wave (wave-level k-split)
#define NT   (KW / BK)          // 64 tiles per wave
#define NBLK (N_TOKENS / 64)    // 256 blocks = 1 per CU

// ---------------------------------------------------------------------------
// Fused router: GEMM + softmax + top-2 + per-block p/f sums in ONE kernel.
//
// Block = 64 tokens, 256 threads = 4 waves. Wave wv computes the FULL
// 64 tokens x 64 experts tile for k in [wv*1024, wv*1024+1024):
//   - 8x8 register micro-tile per thread (tg=lane&7 tokens, eg=lane>>3 experts)
//   - per k-step: 4 ds_read_b128 -> 64 v_fmac_f32  (VALU-bound, 128cyc vs ~16cyc LDS)
//   - double-buffered per-wave LDS staging, NO __syncthreads in main loop
//     (waves fully independent; compiler handles same-wave lgkmcnt ordering)
// Epilogue: barrier, 4 wave-tiles -> LDS, 4-way k-reduce, softmax/top2 with
// ballot-argmax (ties -> lowest index, matching jax.lax.top_k), per-lane
// p-accumulation (lane = expert), block p/f sums -> block_sums (no atomics).
// ---------------------------------------------------------------------------
__global__ void __launch_bounds__(256)
router_fused(const float* __restrict__ x, const float* __restrict__ w,
             float* __restrict__ out, float* __restrict__ block_sums) {
    // staging: per wave 2 x [BK][LD] for x and 2 x [BK][LD] for w = 4*BK*LD floats
    // epilogue reuses [0, 16384) as 4 x [64][64] acc tiles; p/f sums at the end
    __shared__ float smem[4 * 4 * BK * LD + 2 * 4 * N_EXP];   // 17408 + 512 floats

    const int tid  = threadIdx.x;
    const int wv   = tid >> 6;
    const int lane = tid & 63;
    const int tok0 = blockIdx.x * 64;

    float* xs  = smem + wv * (4 * BK * LD);   // x double-buffer for this wave
    float* wsb = xs + 2 * BK * LD;            // w double-buffer for this wave

    // staging decomposition: lane covers rows {srow, srow+16, srow+32, srow+48},
    // k-chunk skc..skc+3 (float4)
    const int srow = lane >> 2;          // 0..15
    const int skc  = (lane & 3) * 4;     // 0,4,8,12

    // compute decomposition
    const int tg   = lane & 7;
    const int eg   = lane >> 3;
    const int trow = tg * 8;             // first of 8 tokens
    const int ecol = eg * 8;             // first of 8 experts

    const float* xp = x + (size_t)(tok0 + srow) * D_MODEL + (size_t)wv * KW + skc;
    const float* wp = w + (size_t)srow * D_MODEL + (size_t)wv * KW + skc;

    float acc[8][8] = {};

#define LOADR(q, roff) (*(const float4*)((q) + (size_t)(roff) * D_MODEL))
#define STORE_TILE(buf, v, roff) do {                      \
        (buf)[(skc + 0) * LD + srow + (roff)] = (v).x;     \
        (buf)[(skc + 1) * LD + srow + (roff)] = (v).y;     \
        (buf)[(skc + 2) * LD + srow + (roff)] = (v).z;     \
        (buf)[(skc + 3) * LD + srow + (roff)] = (v).w;     \
    } while (0)

    // prologue: tile 0 -> buffer 0
    {
        float4 a0 = LOADR(xp, 0),  a1 = LOADR(xp, 16);
        float4 a2 = LOADR(xp, 32), a3 = LOADR(xp, 48);
        float4 b0 = LOADR(wp, 0),  b1 = LOADR(wp, 16);
        float4 b2 = LOADR(wp, 32), b3 = LOADR(wp, 48);
        STORE_TILE(xs, a0, 0);  STORE_TILE(xs, a1, 16);
        STORE_TILE(xs, a2, 32); STORE_TILE(xs, a3, 48);
        STORE_TILE(wsb, b0, 0);  STORE_TILE(wsb, b1, 16);
        STORE_TILE(wsb, b2, 32); STORE_TILE(wsb, b3, 48);
    }

    auto compute_tile = [&](const float* xb, const float* wb) {
#pragma unroll
        for (int k = 0; k < BK; ++k) {
            const float* xr = xb + k * LD + trow;
            const float* wr = wb + k * LD + ecol;
            float4 xa = *(const float4*)xr;
            float4 xc = *(const float4*)(xr + 4);
            float4 wa = *(const float4*)wr;
            float4 wc = *(const float4*)(wr + 4);
            float xf[8] = {xa.x, xa.y, xa.z, xa.w, xc.x, xc.y, xc.z, xc.w};
            float wf[8] = {wa.x, wa.y, wa.z, wa.w, wc.x, wc.y, wc.z, wc.w};
#pragma unroll
            for (int i = 0; i < 8; ++i)
#pragma unroll
                for (int j = 0; j < 8; ++j)
                    acc[i][j] = fmaf(xf[i], wf[j], acc[i][j]);
        }
    };

#pragma unroll 2
    for (int t = 0; t < NT - 1; ++t) {
        float* xb = xs  + (t & 1) * (BK * LD);
        float* wb = wsb + (t & 1) * (BK * LD);
        float* xn = xs  + ((t + 1) & 1) * (BK * LD);
        float* wn = wsb + ((t + 1) & 1) * (BK * LD);

        // issue next tile's global loads (HBM latency hides under 2048cyc of FMA)
        const float* xq = xp + (t + 1) * BK;
        const float* wq = wp + (t + 1) * BK;
        float4 a0 = LOADR(xq, 0),  a1 = LOADR(xq, 16);
        float4 a2 = LOADR(xq, 32), a3 = LOADR(xq, 48);
        float4 b0 = LOADR(wq, 0),  b1 = LOADR(wq, 16);
        float4 b2 = LOADR(wq, 32), b3 = LOADR(wq, 48);

        compute_tile(xb, wb);

        STORE_TILE(xn, a0, 0);  STORE_TILE(xn, a1, 16);
        STORE_TILE(xn, a2, 32); STORE_TILE(xn, a3, 48);
        STORE_TILE(wn, b0, 0);  STORE_TILE(wn, b1, 16);
        STORE_TILE(wn, b2, 32); STORE_TILE(wn, b3, 48);
    }
    compute_tile(xs + ((NT - 1) & 1) * (BK * LD), wsb + ((NT - 1) & 1) * (BK * LD));

    // ---- epilogue: cross-wave k-reduce + softmax/top2 ----
    __syncthreads();                       // all waves done with staging regions

    float* tile = smem + wv * 4096;        // wave's 64x64 partial tile
#pragma unroll
    for (int i = 0; i < 8; ++i) {
        *(float4*)&tile[(trow + i) * 64 + ecol] =
            make_float4(acc[i][0], acc[i][1], acc[i][2], acc[i][3]);
        *(float4*)&tile[(trow + i) * 64 + ecol + 4] =
            make_float4(acc[i][4], acc[i][5], acc[i][6], acc[i][7]);
    }
    __syncthreads();

    float p_acc = 0.f, f_acc = 0.f;        // lane = expert
#pragma unroll 1
    for (int it = 0; it < 16; ++it) {
        const int tl = wv * 16 + it;       // local token
        const int o  = tl * 64 + lane;
        float logit = smem[o] + smem[4096 + o] + smem[8192 + o] + smem[12288 + o];

        // top-1: value max-reduce, then ballot -> lowest tied index
        float m = logit;
#pragma unroll
        for (int off = 32; off; off >>= 1)
            m = fmaxf(m, __shfl_xor(m, off, 64));
        unsigned long long b1 = __ballot(logit == m);
        int i1 = __ffsll(b1) - 1;

        float p = expf(logit - m);
        float denom = p;
#pragma unroll
        for (int off = 32; off; off >>= 1)
            denom += __shfl_xor(denom, off, 64);

        p_acc += p / denom;                // router_probs[token][lane]
        if (lane == i1) f_acc += 1.f;

        // top-2: mask i1, repeat
        float lx = (lane == i1) ? -__builtin_inff() : logit;
        float m2 = lx;
#pragma unroll
        for (int off = 32; off; off >>= 1)
            m2 = fmaxf(m2, __shfl_xor(m2, off, 64));
        unsigned long long b2 = __ballot(lx == m2);
        int i2 = __ffsll(b2) - 1;

        if (lane == 0) {
            float p1 = 1.0f / denom;               // exp(m-m)/denom
            float p2 = expf(m2 - m) / denom;
            float s12 = p1 + p2;
            int token = tok0 + tl;
            ((float2*)out)[token] = make_float2(p1 / s12, p2 / s12);
            ((float2*)(out + 2 * N_TOKENS))[token] =
                make_float2((float)i1, (float)i2);
        }
    }

    // block-level p/f sums -> block_sums (no atomics)
    float* pf = smem + 4 * 4 * BK * LD;
    pf[wv * 64 + lane]       = p_acc;
    pf[256 + wv * 64 + lane] = f_acc;
    __syncthreads();
    if (tid < N_EXP) {
        float ps = pf[tid] + pf[64 + tid] + pf[128 + tid] + pf[192 + tid];
        float fs = pf[256 + tid] + pf[320 + tid] + pf[384 + tid] + pf[448 + tid];
        block_sums[(size_t)blockIdx.x * 128 + tid]      = ps;
        block_sums[(size_t)blockIdx.x * 128 + 64 + tid] = fs;
    }
}

// ---------------------------------------------------------------------------
// Final: reduce 256 blocks' p/f sums, loss = 0.01 * sum_e (f_e/N)*(p_e/N).
// ---------------------------------------------------------------------------
__global__ void __launch_bounds__(256)
router_final(const float* __restrict__ block_sums, float* __restrict__ out) {
    __shared__ float sp[4][N_EXP];
    __shared__ float sf[4][N_EXP];

    int tid  = threadIdx.x;
    int wv   = tid >> 6;
    int lane = tid & 63;

    float ps = 0.f, fs = 0.f;
#pragma unroll 8
    for (int b = wv * (NBLK / 4); b < (wv + 1) * (NBLK / 4); ++b) {
        ps += block_sums[(size_t)b * 128 + lane];
        fs += block_sums[(size_t)b * 128 + 64 + lane];
    }
    sp[wv][lane] = ps;
    sf[wv][lane] = fs;
    __syncthreads();

    if (tid < N_EXP) {
        float pt = sp[0][tid] + sp[1][tid] + sp[2][tid] + sp[3][tid];
        float ft = sf[0][tid] + sf[1][tid] + sf[2][tid] + sf[3][tid];
        float v = pt * ft;
#pragma unroll
        for (int off = 1; off < 64; off <<= 1)
            v += __shfl_xor(v, off, 64);
        if (tid == 0)
            out[4 * N_TOKENS] = 0.01f * v / ((float)N_TOKENS * (float)N_TOKENS);
    }
}

// ---------------------------------------------------------------------------
extern "C" void kernel_launch(void* const* d_in, const int* in_sizes, int n_in,
                              void* d_out, int out_size, void* d_ws, size_t ws_size,
                              hipStream_t stream) {
    (void)in_sizes; (void)n_in; (void)out_size; (void)ws_size;
    const float* x = (const float*)d_in[0];
    const float* w = (const float*)d_in[1];
    float* out = (float*)d_out;
    float* block_sums = (float*)d_ws;     // 256 * 128 * 4 B = 128 KB

    router_fused<<<NBLK, 256, 0, stream>>>(x, w, out, block_sums);
    router_final<<<1, 256, 0, stream>>>(block_sums, out);
}